// Round 1
// baseline (307.348 us; speedup 1.0000x reference)
//
#include <hip/hip_runtime.h>
#include <stdint.h>

#define B_   8
#define L_   1024
#define DM   512
#define DI   1024
#define DS   16
#define DTR  32
#define M_   (B_*L_)   // 8192 tokens

typedef short v8s __attribute__((ext_vector_type(8)));
typedef short v4s __attribute__((ext_vector_type(4)));
typedef float v4f __attribute__((ext_vector_type(4)));

static __device__ __forceinline__ short f2bf(float f) {
  union { float f; uint32_t u; } v; v.f = f;
  uint32_t r = v.u + 0x7FFFu + ((v.u >> 16) & 1u);
  return (short)(r >> 16);
}

static __device__ __forceinline__ float wsum(float v) {
#pragma unroll
  for (int o = 32; o > 0; o >>= 1) v += __shfl_xor(v, o, 64);
  return v;
}

// ---------------- prep: cast x, W_in[:1024], W_x[:48], W_dt to bf16 ----------
__global__ __launch_bounds__(256) void k_prep(const float* __restrict__ x,
                                              const float* __restrict__ w_in,
                                              const float* __restrict__ w_x,
                                              const float* __restrict__ w_dt,
                                              short* xb, short* wib, short* wxb, short* wdtb) {
  int idx = blockIdx.x * 256 + threadIdx.x;
  const int n0 = M_ * DM, n1 = DI * DM, n2 = 48 * DI, n3 = DI * DTR;
  if (idx < n0) { xb[idx] = f2bf(x[idx]); return; }
  idx -= n0;
  if (idx < n1) { wib[idx] = f2bf(w_in[idx]); return; }
  idx -= n1;
  if (idx < n2) { wxb[idx] = f2bf(w_x[idx]); return; }
  idx -= n2;
  if (idx < n3) { wdtb[idx] = f2bf(w_dt[idx]); return; }
}

// ---------------- xi = x @ W_in[:1024].T  (bf16 MFMA, fp32 out) --------------
// wave computes 16(m) x 64(n); A-frag: lane holds A[m=lane&15][k=quad*8+j]
__global__ __launch_bounds__(256) void k_gemm_xi(const short* __restrict__ xb,
                                                 const short* __restrict__ wib,
                                                 float* __restrict__ xi) {
  int wid = blockIdx.x * 4 + (threadIdx.x >> 6);  // 0..8191
  int mtile = wid >> 4, ng = wid & 15;
  int l = threadIdx.x & 63, lm = l & 15, q = l >> 4;
  v4f acc0 = {0,0,0,0}, acc1 = {0,0,0,0}, acc2 = {0,0,0,0}, acc3 = {0,0,0,0};
  const short* ap  = xb  + (size_t)(mtile*16 + lm)*DM + q*8;
  const short* bp0 = wib + (size_t)(ng*64 +  0 + lm)*DM + q*8;
  const short* bp1 = wib + (size_t)(ng*64 + 16 + lm)*DM + q*8;
  const short* bp2 = wib + (size_t)(ng*64 + 32 + lm)*DM + q*8;
  const short* bp3 = wib + (size_t)(ng*64 + 48 + lm)*DM + q*8;
#pragma unroll
  for (int kk = 0; kk < DM/32; ++kk) {
    v8s a = *(const v8s*)(ap + kk*32);
    acc0 = __builtin_amdgcn_mfma_f32_16x16x32_bf16(a, *(const v8s*)(bp0 + kk*32), acc0, 0,0,0);
    acc1 = __builtin_amdgcn_mfma_f32_16x16x32_bf16(a, *(const v8s*)(bp1 + kk*32), acc1, 0,0,0);
    acc2 = __builtin_amdgcn_mfma_f32_16x16x32_bf16(a, *(const v8s*)(bp2 + kk*32), acc2, 0,0,0);
    acc3 = __builtin_amdgcn_mfma_f32_16x16x32_bf16(a, *(const v8s*)(bp3 + kk*32), acc3, 0,0,0);
  }
  int row0 = mtile*16 + q*4;
  int colb = ng*64 + lm;
#pragma unroll
  for (int r = 0; r < 4; ++r) {
    size_t ro = (size_t)(row0 + r) * DI;
    xi[ro + colb +  0] = acc0[r];
    xi[ro + colb + 16] = acc1[r];
    xi[ro + colb + 32] = acc2[r];
    xi[ro + colb + 48] = acc3[r];
  }
}

// ---------------- causal depthwise conv + silu -------------------------------
__global__ __launch_bounds__(256) void k_conv(const float* __restrict__ xi,
                                              const float* __restrict__ conv_w,
                                              const float* __restrict__ conv_b,
                                              float* __restrict__ xc,
                                              short* __restrict__ xcb) {
  int idx = blockIdx.x * 256 + threadIdx.x;   // (b,t,d/4): 2,097,152 total
  int d4 = idx & 255; int rest = idx >> 8;
  int t = rest & (L_-1); int b = rest >> 10;
  int d = d4 * 4;
  v4f cw0 = *(const v4f*)(conv_w + (d+0)*4);
  v4f cw1 = *(const v4f*)(conv_w + (d+1)*4);
  v4f cw2 = *(const v4f*)(conv_w + (d+2)*4);
  v4f cw3 = *(const v4f*)(conv_w + (d+3)*4);
  v4f acc = *(const v4f*)(conv_b + d);
#pragma unroll
  for (int k = 0; k < 4; ++k) {
    int tt = t + k - 3;
    if (tt >= 0) {
      v4f xv = *(const v4f*)(xi + ((size_t)(b*L_ + tt))*DI + d);
      acc[0] += cw0[k]*xv[0]; acc[1] += cw1[k]*xv[1];
      acc[2] += cw2[k]*xv[2]; acc[3] += cw3[k]*xv[3];
    }
  }
  v4f out; v4s ob;
#pragma unroll
  for (int i = 0; i < 4; ++i) {
    float s = acc[i] / (1.f + __expf(-acc[i]));
    out[i] = s; ob[i] = f2bf(s);
  }
  size_t o = (size_t)idx * 4;
  *(v4f*)(xc + o) = out;
  *(v4s*)(xcb + o) = ob;
}

// ---------------- dbc = xc @ W_x[:48].T  (bf16 MFMA) -------------------------
__global__ __launch_bounds__(256) void k_gemm_dbc(const short* __restrict__ xcb,
                                                  const short* __restrict__ wxb,
                                                  float* __restrict__ dbc,
                                                  short* __restrict__ dbc32b) {
  int mtile = blockIdx.x * 4 + (threadIdx.x >> 6);  // 0..511
  int l = threadIdx.x & 63, lm = l & 15, q = l >> 4;
  v4f a0 = {0,0,0,0}, a1 = {0,0,0,0}, a2 = {0,0,0,0};
  const short* ap  = xcb + (size_t)(mtile*16 + lm)*DI + q*8;
  const short* bp0 = wxb + (size_t)( 0 + lm)*DI + q*8;
  const short* bp1 = wxb + (size_t)(16 + lm)*DI + q*8;
  const short* bp2 = wxb + (size_t)(32 + lm)*DI + q*8;
#pragma unroll 8
  for (int kk = 0; kk < DI/32; ++kk) {
    v8s a = *(const v8s*)(ap + kk*32);
    a0 = __builtin_amdgcn_mfma_f32_16x16x32_bf16(a, *(const v8s*)(bp0 + kk*32), a0, 0,0,0);
    a1 = __builtin_amdgcn_mfma_f32_16x16x32_bf16(a, *(const v8s*)(bp1 + kk*32), a1, 0,0,0);
    a2 = __builtin_amdgcn_mfma_f32_16x16x32_bf16(a, *(const v8s*)(bp2 + kk*32), a2, 0,0,0);
  }
  int row0 = mtile*16 + q*4;
#pragma unroll
  for (int r = 0; r < 4; ++r) {
    int row = row0 + r;
    dbc[(size_t)row*48 + lm +  0] = a0[r];
    dbc[(size_t)row*48 + lm + 16] = a1[r];
    dbc[(size_t)row*48 + lm + 32] = a2[r];
    dbc32b[(size_t)row*32 + lm +  0] = f2bf(a0[r]);
    dbc32b[(size_t)row*32 + lm + 16] = f2bf(a1[r]);
  }
}

// ---------------- dt = softplus(dbc[:, :32] @ W_dt.T + b_dt) -----------------
__global__ __launch_bounds__(256) void k_gemm_dt(const short* __restrict__ dbc32b,
                                                 const short* __restrict__ wdtb,
                                                 const float* __restrict__ b_dt,
                                                 float* __restrict__ dt) {
  int wid = blockIdx.x * 4 + (threadIdx.x >> 6);  // 0..8191
  int mtile = wid >> 4, ng = wid & 15;
  int l = threadIdx.x & 63, lm = l & 15, q = l >> 4;
  v8s a = *(const v8s*)(dbc32b + (size_t)(mtile*16 + lm)*DTR + q*8);
  v4f acc[4];
#pragma unroll
  for (int ns = 0; ns < 4; ++ns) {
    v4f z = {0,0,0,0};
    v8s bb = *(const v8s*)(wdtb + (size_t)(ng*64 + ns*16 + lm)*DTR + q*8);
    acc[ns] = __builtin_amdgcn_mfma_f32_16x16x32_bf16(a, bb, z, 0,0,0);
  }
  int row0 = mtile*16 + q*4;
#pragma unroll
  for (int ns = 0; ns < 4; ++ns) {
    int col = ng*64 + ns*16 + lm;
    float bd = b_dt[col];
#pragma unroll
    for (int r = 0; r < 4; ++r) {
      float v = acc[ns][r] + bd;
      float sp = (v > 15.f) ? v : log1pf(__expf(v));
      dt[(size_t)(row0 + r)*DI + col] = sp;
    }
  }
}

// ---------------- per-chunk dt sums ------------------------------------------
__global__ __launch_bounds__(256) void k_csum(const float* __restrict__ dt,
                                              float* __restrict__ csum) {
  int bc = blockIdx.x;            // b*16 + chunk
  int b = bc >> 4, ch = bc & 15;
#pragma unroll
  for (int dd = 0; dd < 4; ++dd) {
    int d = dd*256 + threadIdx.x;
    const float* p = dt + ((size_t)(b*L_ + ch*64))*DI + d;
    float s = 0.f;
    for (int i = 0; i < 64; ++i) s += p[(size_t)i*DI];
    csum[(size_t)bc*DI + d] = s;
  }
}

// ---------------- z_last and C_last ------------------------------------------
__global__ __launch_bounds__(256) void k_zc(const float* __restrict__ x,
                                            const float* __restrict__ w_in,
                                            const float* __restrict__ xc,
                                            const float* __restrict__ w_x,
                                            float* __restrict__ zlast,
                                            float* __restrict__ clast) {
  int l = threadIdx.x & 63;
  if (blockIdx.x < 2048) {
    int w = blockIdx.x * 4 + (threadIdx.x >> 6);  // 0..8191
    int b = w >> 10, j = w & 1023;
    const v4f* xr = (const v4f*)(x + ((size_t)(b*L_ + L_-1))*DM);
    const v4f* wr = (const v4f*)(w_in + (size_t)(DI + j)*DM);
    float s = 0.f;
#pragma unroll
    for (int i = 0; i < 2; ++i) {
      v4f a = xr[l + 64*i], c = wr[l + 64*i];
      s += a[0]*c[0] + a[1]*c[1] + a[2]*c[2] + a[3]*c[3];
    }
    s = wsum(s);
    if (l == 0) zlast[b*DI + j] = s;
  } else {
    int w2 = (int)(blockIdx.x - 2048) * 4 + (threadIdx.x >> 6);  // 0..127
    int b = w2 >> 4, ss = w2 & 15;
    const v4f* xr = (const v4f*)(xc + ((size_t)(b*L_ + L_-1))*DI);
    const v4f* wr = (const v4f*)(w_x + (size_t)(48 + ss)*DI);
    float s = 0.f;
#pragma unroll
    for (int i = 0; i < 4; ++i) {
      v4f a = xr[l + 64*i], c = wr[l + 64*i];
      s += a[0]*c[0] + a[1]*c[1] + a[2]*c[2] + a[3]*c[3];
    }
    s = wsum(s);
    if (l == 0) clast[b*16 + ss] = s;
  }
}

// ---------------- scan (collapsed to parallel suffix-weighted reduction) -----
// h_final[b,d,s] = sum_t exp(A[d,s]*S_t) * dt_t*u_t * B_t[s],  S_t = suffix sum of dt
// each block: one (b, chunk-of-64-t, 256 d's); accumulates scalar y = h . C_last
__global__ __launch_bounds__(256) void k_scan(const float* __restrict__ dt,
                                              const float* __restrict__ xc,
                                              const float* __restrict__ dbc,
                                              const float* __restrict__ csum,
                                              const float* __restrict__ a_log,
                                              const float* __restrict__ clast,
                                              float* __restrict__ ypre) {
  __shared__ float lB[64*16];
  int bid = blockIdx.x;           // 8 * 16 * 4 = 512
  int b = bid >> 6, rem = bid & 63, ch = rem >> 2, dg = rem & 3;
  int tid = threadIdx.x;
  for (int i = tid; i < 64*16; i += 256) {
    int tl = i >> 4, s = i & 15;
    lB[i] = dbc[((size_t)(b*L_ + ch*64 + tl))*48 + 32 + s];
  }
  __syncthreads();
  int d = dg*256 + tid;
  float S = 0.f;
  for (int c = ch + 1; c < 16; ++c) S += csum[(size_t)(b*16 + c)*DI + d];
  float As[16];
#pragma unroll
  for (int s = 0; s < 16; ++s) As[s] = -__expf(a_log[d*16 + s]);
  float h[16];
#pragma unroll
  for (int s = 0; s < 16; ++s) h[s] = 0.f;
  const float* dtp = dt + ((size_t)(b*L_ + ch*64))*DI + d;
  const float* xcp = xc + ((size_t)(b*L_ + ch*64))*DI + d;
  for (int tl = 63; tl >= 0; --tl) {
    float dtv = dtp[(size_t)tl*DI];
    float u   = xcp[(size_t)tl*DI];
    float c = dtv * u;
#pragma unroll
    for (int s = 0; s < 16; ++s)
      h[s] += __expf(As[s]*S) * (c * lB[tl*16 + s]);
    S += dtv;
  }
  float yp = 0.f;
#pragma unroll
  for (int s = 0; s < 16; ++s) yp += h[s] * clast[b*16 + s];
  atomicAdd(ypre + b*DI + d, yp);
}

// ---------------- y_last = (ypre + D*xc_last) * silu(z_last) -----------------
__global__ __launch_bounds__(256) void k_ylast(const float* __restrict__ ypre,
                                               const float* __restrict__ xc,
                                               const float* __restrict__ Dp,
                                               const float* __restrict__ zlast,
                                               float* __restrict__ ylast) {
  int idx = blockIdx.x * 256 + threadIdx.x;  // 8192
  int b = idx >> 10, d = idx & 1023;
  float xcl = xc[((size_t)(b*L_ + L_-1))*DI + d];
  float y = ypre[idx] + Dp[d] * xcl;
  float z = zlast[idx];
  y *= z / (1.f + __expf(-z));
  ylast[idx] = y;
}

// ---------------- out_last = y_last @ W_out.T --------------------------------
__global__ __launch_bounds__(256) void k_out(const float* __restrict__ ylast,
                                             const float* __restrict__ w_out,
                                             float* __restrict__ olast) {
  int w = blockIdx.x * 4 + (threadIdx.x >> 6);  // 4096
  int l = threadIdx.x & 63;
  int b = w >> 9, i = w & 511;
  const v4f* yr = (const v4f*)(ylast + (size_t)b*DI);
  const v4f* wr = (const v4f*)(w_out + (size_t)i*DI);
  float s = 0.f;
#pragma unroll
  for (int k = 0; k < 4; ++k) {
    v4f a = yr[l + 64*k], c = wr[l + 64*k];
    s += a[0]*c[0] + a[1]*c[1] + a[2]*c[2] + a[3]*c[3];
  }
  s = wsum(s);
  if (l == 0) olast[b*DM + i] = s;
}

// ---------------- layer norm over last token ---------------------------------
__global__ __launch_bounds__(256) void k_ln(const float* __restrict__ olast,
                                            const float* __restrict__ g,
                                            const float* __restrict__ be,
                                            float* __restrict__ lastn) {
  __shared__ float s1[256], s2[256];
  int b = blockIdx.x, tid = threadIdx.x;
  float v0 = olast[b*DM + tid], v1 = olast[b*DM + 256 + tid];
  s1[tid] = v0 + v1; s2[tid] = v0*v0 + v1*v1;
  __syncthreads();
  for (int o = 128; o > 0; o >>= 1) {
    if (tid < o) { s1[tid] += s1[tid+o]; s2[tid] += s2[tid+o]; }
    __syncthreads();
  }
  float mu = s1[0] / 512.f;
  float var = s2[0] / 512.f - mu*mu;
  float inv = 1.f / sqrtf(var + 1e-5f);
  lastn[b*DM + tid]       = (v0 - mu)*inv*g[tid]       + be[tid];
  lastn[b*DM + 256 + tid] = (v1 - mu)*inv*g[tid + 256] + be[tid + 256];
}

// ---------------- head GEMM --------------------------------------------------
__global__ __launch_bounds__(256) void k_head(const float* __restrict__ lastn,
                                              const float* __restrict__ hw,
                                              const float* __restrict__ hb,
                                              float* __restrict__ out) {
  int w = blockIdx.x * 4 + (threadIdx.x >> 6);  // 4096
  int l = threadIdx.x & 63;
  int b = w >> 9, o = w & 511;
  const v4f* xr = (const v4f*)(lastn + (size_t)b*DM);
  const v4f* wr = (const v4f*)(hw + (size_t)o*DM);
  float s = 0.f;
#pragma unroll
  for (int k = 0; k < 2; ++k) {
    v4f a = xr[l + 64*k], c = wr[l + 64*k];
    s += a[0]*c[0] + a[1]*c[1] + a[2]*c[2] + a[3]*c[3];
  }
  s = wsum(s);
  if (l == 0) out[b*DM + o] = s + hb[o];
}

extern "C" void kernel_launch(void* const* d_in, const int* in_sizes, int n_in,
                              void* d_out, int out_size, void* d_ws, size_t ws_size,
                              hipStream_t stream) {
  const float* x      = (const float*)d_in[0];
  const float* w_in   = (const float*)d_in[1];
  const float* conv_w = (const float*)d_in[2];
  const float* conv_b = (const float*)d_in[3];
  const float* w_x    = (const float*)d_in[4];
  const float* w_dt   = (const float*)d_in[5];
  const float* b_dt   = (const float*)d_in[6];
  const float* a_log  = (const float*)d_in[7];
  const float* Dp     = (const float*)d_in[8];
  const float* w_out  = (const float*)d_in[9];
  const float* ln_g   = (const float*)d_in[10];
  const float* ln_b   = (const float*)d_in[11];
  const float* head_W = (const float*)d_in[12];
  const float* head_b = (const float*)d_in[13];
  float* out = (float*)d_out;

  char* ws = (char*)d_ws;
  size_t off = 0;
  auto alloc = [&](size_t bytes) { void* p = ws + off; off += (bytes + 255) & ~(size_t)255; return p; };
  short* xb     = (short*)alloc((size_t)M_*DM*2);
  short* wib    = (short*)alloc((size_t)DI*DM*2);
  short* wxb    = (short*)alloc((size_t)48*DI*2);
  short* wdtb   = (short*)alloc((size_t)DI*DTR*2);
  float* xi     = (float*)alloc((size_t)M_*DI*4);   // also reused as dt (aliased)
  float* xc     = (float*)alloc((size_t)M_*DI*4);
  short* xcb    = (short*)alloc((size_t)M_*DI*2);
  float* dbc    = (float*)alloc((size_t)M_*48*4);
  short* dbc32b = (short*)alloc((size_t)M_*32*2);
  float* csum   = (float*)alloc((size_t)B_*16*DI*4);
  float* ypre   = (float*)alloc((size_t)B_*DI*4);
  float* zlast  = (float*)alloc((size_t)B_*DI*4);
  float* clast  = (float*)alloc((size_t)B_*DS*4);
  float* ylast  = (float*)alloc((size_t)B_*DI*4);
  float* olast  = (float*)alloc((size_t)B_*DM*4);
  float* lastn  = (float*)alloc((size_t)B_*DM*4);
  float* dt     = xi;  // xi is dead after k_conv; dt written after

  k_prep<<<18752, 256, 0, stream>>>(x, w_in, w_x, w_dt, xb, wib, wxb, wdtb);
  k_gemm_xi<<<2048, 256, 0, stream>>>(xb, wib, xi);
  k_conv<<<8192, 256, 0, stream>>>(xi, conv_w, conv_b, xc, xcb);
  k_gemm_dbc<<<128, 256, 0, stream>>>(xcb, wxb, dbc, dbc32b);
  k_gemm_dt<<<2048, 256, 0, stream>>>(dbc32b, wdtb, b_dt, dt);
  k_csum<<<128, 256, 0, stream>>>(dt, csum);
  k_zc<<<2080, 256, 0, stream>>>(x, w_in, xc, w_x, zlast, clast);
  hipMemsetAsync(ypre, 0, (size_t)B_*DI*4, stream);
  k_scan<<<512, 256, 0, stream>>>(dt, xc, dbc, csum, a_log, clast, ypre);
  k_ylast<<<32, 256, 0, stream>>>(ypre, xc, Dp, zlast, ylast);
  k_out<<<1024, 256, 0, stream>>>(ylast, w_out, olast);
  k_ln<<<8, 256, 0, stream>>>(olast, ln_g, ln_b, lastn);
  k_head<<<1024, 256, 0, stream>>>(lastn, head_W, head_b, out);
}